// Round 2
// baseline (2261.325 us; speedup 1.0000x reference)
//
#include <hip/hip_runtime.h>

// NucleiGNN fused forward: B=2048 molecules, one block per molecule.
// Input float dtype (bf16 vs f32) is detected ON DEVICE from Wq's bit
// pattern; both template instantiations are launched and the wrong one
// exits immediately (block-uniform early return, no barriers crossed).
// h[64][128] in registers (4 rows x 4 cols per thread, 512 threads);
// hn/q/k/v f32 tiles in LDS (row stride 132 to break bank aliasing).
// q buffer is reused as msg buffer (per-head halves) to save 32KB LDS.

#define NBATCH 2048
#define NATOM  64
#define NF     128
#define NLAYER 3
#define STR    132   // f32 row stride for 64x128 LDS tiles (132 mod 32 = 4)
#define ASTR   65    // attention row stride
#define NTH    512

__device__ __forceinline__ float bf2f(unsigned short u) {
    union { unsigned int i; float f; } v; v.i = ((unsigned int)u) << 16; return v.f;
}
__device__ __forceinline__ unsigned short f2bf(float f) {
    union { float ff; unsigned int i; } v; v.ff = f;
    unsigned int x = v.i;
    if ((x & 0x7f800000u) == 0x7f800000u) return (unsigned short)(x >> 16);
    return (unsigned short)((x + 0x7fffu + ((x >> 16) & 1u)) >> 16);
}

template<bool BF16>
__device__ __forceinline__ float ldT(const void* p, int i) {
    if constexpr (BF16) return bf2f(((const unsigned short*)p)[i]);
    else                return ((const float*)p)[i];
}
template<bool BF16>
__device__ __forceinline__ float4 ld4T(const void* p, int i) {
    if constexpr (BF16) {
        ushort4 v = *(const ushort4*)((const unsigned short*)p + i);
        return make_float4(bf2f(v.x), bf2f(v.y), bf2f(v.z), bf2f(v.w));
    } else {
        return *(const float4*)((const float*)p + i);
    }
}

// [64,128](f32, LDS) @ [128,128](dtype, global) -> acc[4][4] tile
// thread tile: rows r0..r0+3, cols fq*4..fq*4+3
template<bool BF16>
__device__ __forceinline__ void mm16(const float* __restrict__ src,
                                     const void* __restrict__ W, int wbase,
                                     float acc[4][4], int r0, int fq)
{
    #pragma unroll 4
    for (int kk4 = 0; kk4 < 32; ++kk4) {
        float a[4][4];
        #pragma unroll
        for (int i = 0; i < 4; ++i) {
            float4 av = *(const float4*)&src[(r0 + i) * STR + kk4 * 4];
            a[i][0] = av.x; a[i][1] = av.y; a[i][2] = av.z; a[i][3] = av.w;
        }
        #pragma unroll
        for (int kc = 0; kc < 4; ++kc) {
            float4 wv = ld4T<BF16>(W, wbase + (kk4 * 4 + kc) * NF + fq * 4);
            #pragma unroll
            for (int i = 0; i < 4; ++i) {
                acc[i][0] += a[i][kc] * wv.x;
                acc[i][1] += a[i][kc] * wv.y;
                acc[i][2] += a[i][kc] * wv.z;
                acc[i][3] += a[i][kc] * wv.w;
            }
        }
    }
}

// LayerNorm of register-resident h into buf (or dtype out if outp != nullptr)
template<bool BF16>
__device__ __forceinline__ void block_ln(const float (&h)[4][4], float* __restrict__ buf,
                                         float* __restrict__ part, float* __restrict__ part2,
                                         float* __restrict__ mu_s, float* __restrict__ rs_s,
                                         int t, int r0, int fq,
                                         void* __restrict__ outp, int obase)
{
    #pragma unroll
    for (int i = 0; i < 4; ++i)
        *(float4*)&buf[(r0 + i) * STR + fq * 4] = make_float4(h[i][0], h[i][1], h[i][2], h[i][3]);
    __syncthreads();
    {
        int r = t >> 3, q = t & 7;   // 8 threads per row, 16 elems each
        const float* p = &buf[r * STR + q * 16];
        float s = 0.f, s2 = 0.f;
        #pragma unroll
        for (int j = 0; j < 16; ++j) { float x = p[j]; s += x; s2 += x * x; }
        part[r * 8 + q] = s; part2[r * 8 + q] = s2;
    }
    __syncthreads();
    if (t < 64) {
        float s = 0.f, s2 = 0.f;
        #pragma unroll
        for (int q = 0; q < 8; ++q) { s += part[t * 8 + q]; s2 += part2[t * 8 + q]; }
        float mu = s * (1.f / 128.f);
        float var = s2 * (1.f / 128.f) - mu * mu;
        mu_s[t] = mu; rs_s[t] = rsqrtf(fmaxf(var, 0.f) + 1e-5f);
    }
    __syncthreads();
    if (outp == nullptr) {
        #pragma unroll
        for (int i = 0; i < 4; ++i) {
            float mu = mu_s[r0 + i], rs = rs_s[r0 + i];
            *(float4*)&buf[(r0 + i) * STR + fq * 4] =
                make_float4((h[i][0]-mu)*rs, (h[i][1]-mu)*rs, (h[i][2]-mu)*rs, (h[i][3]-mu)*rs);
        }
        __syncthreads();
    } else {
        #pragma unroll
        for (int i = 0; i < 4; ++i) {
            float mu = mu_s[r0 + i], rs = rs_s[r0 + i];
            int idx = obase + (r0 + i) * NF + fq * 4;
            if constexpr (BF16) {
                ushort4 o;
                o.x = f2bf((h[i][0]-mu)*rs); o.y = f2bf((h[i][1]-mu)*rs);
                o.z = f2bf((h[i][2]-mu)*rs); o.w = f2bf((h[i][3]-mu)*rs);
                *(ushort4*)((unsigned short*)outp + idx) = o;
            } else {
                *(float4*)((float*)outp + idx) =
                    make_float4((h[i][0]-mu)*rs, (h[i][1]-mu)*rs, (h[i][2]-mu)*rs, (h[i][3]-mu)*rs);
            }
        }
    }
}

template<bool BF16>
__global__ __launch_bounds__(NTH)
void gnn_fused(const void* __restrict__ coords,
               const int* __restrict__ species,
               const unsigned char* __restrict__ maskraw,
               const void* __restrict__ embed,
               const void* __restrict__ Wq,
               const void* __restrict__ Wk,
               const void* __restrict__ Wv,
               const void* __restrict__ Wo,
               const void* __restrict__ We,
               const void* __restrict__ Wf,
               const void* __restrict__ bfb,
               void* __restrict__ out)
{
    // ---- dtype signature check (block-uniform; wrong instantiation exits) ----
    {
        const unsigned int* w = (const unsigned int*)Wq;
        bool isbf = true;
        #pragma unroll
        for (int i = 0; i < 16; ++i) {
            unsigned int e = (w[i] >> 7) & 0xFFu;  // bf16[0] exponent if bf16-packed
            isbf = isbf && (e >= 0x60u && e <= 0x7Eu);
        }
        if (isbf != BF16) return;
    }

    extern __shared__ float smem[];
    float* hn    = smem;                  // 64*132
    float* qm    = hn + NATOM * STR;      // 64*132 (q, then msg)
    float* kb    = qm + NATOM * STR;      // 64*132
    float* vb    = kb + NATOM * STR;      // 64*132
    float* ah    = vb + NATOM * STR;      // 64*65 attn probs (per head)
    float* cs    = ah + NATOM * ASTR;     // 64*4 coords
    float* wel   = cs + NATOM * 4;        // 48 We (f32)
    float* mu_s  = wel + 48;              // 64
    float* rs_s  = mu_s + NATOM;          // 64
    float* part  = rs_s + NATOM;          // 64*8
    float* part2 = part + NATOM * 8;      // 64*8
    int*   lenp  = (int*)(part2 + NATOM * 8);

    const int t  = threadIdx.x;
    const int b  = blockIdx.x;
    const int fq = t & 31;        // col group: cols fq*4..fq*4+3
    const int rg = t >> 5;        // row group: rows rg*4..rg*4+3
    const int r0 = rg * 4;

    // ---- init: coords, We, mask length ----
    if (t < 64) {
        cs[t * 4 + 0] = ldT<BF16>(coords, (b * NATOM + t) * 3 + 0);
        cs[t * 4 + 1] = ldT<BF16>(coords, (b * NATOM + t) * 3 + 1);
        cs[t * 4 + 2] = ldT<BF16>(coords, (b * NATOM + t) * 3 + 2);
    }
    if (t >= 64 && t < 64 + 42) wel[t - 64] = ldT<BF16>(We, t - 64);
    if (t < 64) {
        // mask element format detection: first elems are guaranteed true (len >= 32)
        unsigned int w0 = *(const unsigned int*)maskraw;
        bool f;
        if (w0 == 1u)               f = ((const int*)maskraw)[b * NATOM + t] != 0;          // int32
        else if (w0 == 0x01010101u) f = maskraw[b * NATOM + t] != 0;                        // u8/bool
        else if (w0 == 0x3F800000u) f = ((const float*)maskraw)[b * NATOM + t] != 0.f;      // f32
        else                        f = ((const unsigned short*)maskraw)[b * NATOM + t] != 0; // 16-bit
        unsigned long long bal = __ballot(f);
        if (t == 0) *lenp = (int)__popcll(bal);
    }

    // ---- h0 = embed[species-1] ----
    float h[4][4];
    #pragma unroll
    for (int i = 0; i < 4; ++i) {
        int row = r0 + i;
        int sp = species[b * NATOM + row];
        float4 ev = ld4T<BF16>(embed, (sp - 1) * NF + fq * 4);
        h[i][0] = ev.x; h[i][1] = ev.y; h[i][2] = ev.z; h[i][3] = ev.w;
    }
    __syncthreads();
    const int len = *lenp;
    #pragma unroll
    for (int i = 0; i < 4; ++i)
        if (r0 + i >= len) { h[i][0] = 0.f; h[i][1] = 0.f; h[i][2] = 0.f; h[i][3] = 0.f; }

    for (int l = 0; l < NLAYER; ++l) {
        // hn = LN(h)
        block_ln<BF16>(h, hn, part, part2, mu_s, rs_s, t, r0, fq, nullptr, 0);

        // q, k, v = hn @ W{q,k,v}[l]
        {
            float acc[4][4];
            #pragma unroll
            for (int i = 0; i < 4; ++i) { acc[i][0]=acc[i][1]=acc[i][2]=acc[i][3]=0.f; }
            mm16<BF16>(hn, Wq, l * NF * NF, acc, r0, fq);
            #pragma unroll
            for (int i = 0; i < 4; ++i)
                *(float4*)&qm[(r0 + i) * STR + fq * 4] = make_float4(acc[i][0],acc[i][1],acc[i][2],acc[i][3]);
            #pragma unroll
            for (int i = 0; i < 4; ++i) { acc[i][0]=acc[i][1]=acc[i][2]=acc[i][3]=0.f; }
            mm16<BF16>(hn, Wk, l * NF * NF, acc, r0, fq);
            #pragma unroll
            for (int i = 0; i < 4; ++i)
                *(float4*)&kb[(r0 + i) * STR + fq * 4] = make_float4(acc[i][0],acc[i][1],acc[i][2],acc[i][3]);
            #pragma unroll
            for (int i = 0; i < 4; ++i) { acc[i][0]=acc[i][1]=acc[i][2]=acc[i][3]=0.f; }
            mm16<BF16>(hn, Wv, l * NF * NF, acc, r0, fq);
            #pragma unroll
            for (int i = 0; i < 4; ++i)
                *(float4*)&vb[(r0 + i) * STR + fq * 4] = make_float4(acc[i][0],acc[i][1],acc[i][2],acc[i][3]);
        }
        __syncthreads();

        // ---- attention, per head ----
        for (int hd = 0; hd < 2; ++hd) {
            const int hoff = hd * 64;
            // logits: thread -> row n = t>>3, cols m = (t&7) + 8*j, j<8
            const int n = t >> 3, mq = t & 7;
            float we_[7];
            #pragma unroll
            for (int e = 0; e < 7; ++e) we_[e] = wel[l * 14 + e * 2 + hd];
            float lg[8];
            #pragma unroll
            for (int j = 0; j < 8; ++j) lg[j] = 0.f;
            #pragma unroll
            for (int dc = 0; dc < 4; ++dc) {
                float qr[16];
                #pragma unroll
                for (int x = 0; x < 4; ++x) {
                    float4 v4 = *(const float4*)&qm[n * STR + hoff + dc * 16 + x * 4];
                    qr[x*4+0]=v4.x; qr[x*4+1]=v4.y; qr[x*4+2]=v4.z; qr[x*4+3]=v4.w;
                }
                #pragma unroll
                for (int j = 0; j < 8; ++j) {
                    const float* kp = &kb[(mq + 8 * j) * STR + hoff + dc * 16];
                    float s = 0.f;
                    #pragma unroll
                    for (int x = 0; x < 4; ++x) {
                        float4 k4 = *(const float4*)&kp[x * 4];
                        s += qr[x*4+0]*k4.x + qr[x*4+1]*k4.y + qr[x*4+2]*k4.z + qr[x*4+3]*k4.w;
                    }
                    lg[j] += s;
                }
            }
            float cnx = cs[n*4+0], cny = cs[n*4+1], cnz = cs[n*4+2];
            #pragma unroll
            for (int j = 0; j < 8; ++j) {
                int m = mq + 8 * j;
                float dx = cnx - cs[m*4+0];
                float dy = cny - cs[m*4+1];
                float dz = cnz - cs[m*4+2];
                float d = sqrtf(dx*dx + dy*dy + dz*dz + 1e-12f);
                float et = expf(-d);
                float s1 = 1.f / (1.f + 7.38905609893065f  * et);  // sigmoid(d-2)
                float s2 = 1.f / (1.f + 54.598150033144236f * et); // sigmoid(d-4)
                float s3 = 1.f / (1.f + 403.4287934927351f  * et); // sigmoid(d-6)
                lg[j] = lg[j] * 0.125f
                      + dx*we_[0] + dy*we_[1] + dz*we_[2] + d*we_[3]
                      + s1*we_[4] + s2*we_[5] + s3*we_[6];
            }
            // masked softmax over m (8 lanes per row)
            float mx = -3e38f;
            #pragma unroll
            for (int j = 0; j < 8; ++j) if (mq + 8*j < len) mx = fmaxf(mx, lg[j]);
            mx = fmaxf(mx, __shfl_xor(mx, 1));
            mx = fmaxf(mx, __shfl_xor(mx, 2));
            mx = fmaxf(mx, __shfl_xor(mx, 4));
            float sm = 0.f;
            #pragma unroll
            for (int j = 0; j < 8; ++j) {
                lg[j] = (mq + 8*j < len) ? expf(lg[j] - mx) : 0.f;
                sm += lg[j];
            }
            sm += __shfl_xor(sm, 1); sm += __shfl_xor(sm, 2); sm += __shfl_xor(sm, 4);
            float inv = (n < len) ? (1.f / sm) : 0.f;  // masked rows -> probs 0 (h zeroed anyway)
            #pragma unroll
            for (int j = 0; j < 8; ++j) ah[n * ASTR + mq + 8*j] = lg[j] * inv;
            __syncthreads();

            // msg_h = attn_h @ v_h -> qm[:, hoff..hoff+63] (q of this head is dead)
            const int dcol = t & 63, rgm = t >> 6;  // 8 rows per thread
            float macc[8];
            #pragma unroll
            for (int i = 0; i < 8; ++i) macc[i] = 0.f;
            #pragma unroll 4
            for (int mc = 0; mc < 16; ++mc) {
                float v0 = vb[(mc*4+0) * STR + hoff + dcol];
                float v1 = vb[(mc*4+1) * STR + hoff + dcol];
                float v2 = vb[(mc*4+2) * STR + hoff + dcol];
                float v3 = vb[(mc*4+3) * STR + hoff + dcol];
                #pragma unroll
                for (int i = 0; i < 8; ++i) {
                    const float* ap = &ah[(rgm*8 + i) * ASTR + mc*4];
                    macc[i] += ap[0]*v0 + ap[1]*v1 + ap[2]*v2 + ap[3]*v3;
                }
            }
            #pragma unroll
            for (int i = 0; i < 8; ++i)
                qm[(rgm*8 + i) * STR + hoff + dcol] = macc[i];
            __syncthreads();
        }

        // h += msg @ Wo[l]
        {
            float acc[4][4];
            #pragma unroll
            for (int i = 0; i < 4; ++i) { acc[i][0]=acc[i][1]=acc[i][2]=acc[i][3]=0.f; }
            mm16<BF16>(qm, Wo, l * NF * NF, acc, r0, fq);
            #pragma unroll
            for (int i = 0; i < 4; ++i) {
                h[i][0] += acc[i][0]; h[i][1] += acc[i][1];
                h[i][2] += acc[i][2]; h[i][3] += acc[i][3];
            }
        }
        // h += tanh(LN(h) @ Wf[l] + bf[l])
        block_ln<BF16>(h, hn, part, part2, mu_s, rs_s, t, r0, fq, nullptr, 0);
        {
            float acc[4][4];
            #pragma unroll
            for (int i = 0; i < 4; ++i) { acc[i][0]=acc[i][1]=acc[i][2]=acc[i][3]=0.f; }
            mm16<BF16>(hn, Wf, l * NF * NF, acc, r0, fq);
            float4 bv = ld4T<BF16>(bfb, l * NF + fq * 4);
            #pragma unroll
            for (int i = 0; i < 4; ++i) {
                h[i][0] += tanhf(acc[i][0] + bv.x);
                h[i][1] += tanhf(acc[i][1] + bv.y);
                h[i][2] += tanhf(acc[i][2] + bv.z);
                h[i][3] += tanhf(acc[i][3] + bv.w);
            }
        }
        // h *= mask
        #pragma unroll
        for (int i = 0; i < 4; ++i)
            if (r0 + i >= len) { h[i][0]=0.f; h[i][1]=0.f; h[i][2]=0.f; h[i][3]=0.f; }
        __syncthreads();  // dense mm16 readers must finish before next-layer LN rewrites hn
    }

    // out = LN(h) in output dtype
    block_ln<BF16>(h, hn, part, part2, mu_s, rs_s, t, r0, fq, out, b * NATOM * NF);
}

static constexpr size_t SMEM_FLOATS =
    (size_t)NATOM * STR * 4 + (size_t)NATOM * ASTR + (size_t)NATOM * 4 + 48
    + NATOM + NATOM + (size_t)NATOM * 8 + (size_t)NATOM * 8 + 4;
static constexpr size_t SMEM_BYTES = SMEM_FLOATS * sizeof(float);

extern "C" void kernel_launch(void* const* d_in, const int* in_sizes, int n_in,
                              void* d_out, int out_size, void* d_ws, size_t ws_size,
                              hipStream_t stream) {
    const void*           coords  = d_in[0];
    const int*            species = (const int*)d_in[1];
    const unsigned char*  maskraw = (const unsigned char*)d_in[2];
    const void*           embed   = d_in[3];
    const void*           Wq      = d_in[4];
    const void*           Wk      = d_in[5];
    const void*           Wv      = d_in[6];
    const void*           Wo      = d_in[7];
    const void*           We      = d_in[8];
    const void*           Wf      = d_in[9];
    const void*           bfb     = d_in[10];

    (void)hipFuncSetAttribute((const void*)gnn_fused<true>,
                              hipFuncAttributeMaxDynamicSharedMemorySize,
                              (int)SMEM_BYTES);
    (void)hipFuncSetAttribute((const void*)gnn_fused<false>,
                              hipFuncAttributeMaxDynamicSharedMemorySize,
                              (int)SMEM_BYTES);
    gnn_fused<true><<<dim3(NBATCH), dim3(NTH), SMEM_BYTES, stream>>>(
        coords, species, maskraw, embed, Wq, Wk, Wv, Wo, We, Wf, bfb, d_out);
    gnn_fused<false><<<dim3(NBATCH), dim3(NTH), SMEM_BYTES, stream>>>(
        coords, species, maskraw, embed, Wq, Wk, Wv, Wo, We, Wf, bfb, d_out);
}